// Round 17
// baseline (350.457 us; speedup 1.0000x reference)
//
#include <hip/hip_runtime.h>

#define LNEPS 1e-5f
#define AEPS 1e-8f
#define SCALE_Q 0.036084391824351615f  // 768^-0.5

typedef unsigned int uint32;
typedef float f32x2 __attribute__((ext_vector_type(2)));

__device__ inline uint32 bfb(float f) {
  __bf16 h = (__bf16)f;
  unsigned short u;
  __builtin_memcpy(&u, &h, 2);
  return (uint32)u;
}

// ---------------- one-time setup: packT Wk | init slots ----------------
__global__ void setup_k(const float* __restrict__ Wk, float* __restrict__ WkT,
                        const float* __restrict__ s0, float* __restrict__ slots) {
  __shared__ float tile[32][33];
  int bb = blockIdx.x, t = threadIdx.x;
  if (bb < 576) {
    int c0 = (bb % 24) * 32, i0 = (bb / 24) * 32;
    int tx = t & 31, ty = t >> 5;
#pragma unroll
    for (int k = 0; k < 4; ++k)
      tile[ty + 8 * k][tx] = Wk[(size_t)(i0 + ty + 8 * k) * 768 + c0 + tx];
    __syncthreads();
#pragma unroll
    for (int k = 0; k < 4; ++k)
      WkT[(size_t)(c0 + ty + 8 * k) * 768 + i0 + tx] = tile[tx][ty + 8 * k];
  } else {
    int idx = (bb - 576) * 256 + t;  // 196608
    slots[idx] = s0[idx % 6144];
  }
}

// ---------------- batched GEMV v3: 64 cols/block, 8-way k-split, 512 thr, grid (12,32) ----
// MODE 0: acc+bias | 1: acc | 2: alpha[r]*acc+beta[r]*bias | 3: relu(acc+bias) | 4: out+=acc+bias
template <bool LN, int MODE>
__global__ void gemv_k(const float* __restrict__ X, const float* __restrict__ W,
                       const float* __restrict__ bias, const float* __restrict__ gamma,
                       const float* __restrict__ beta_ln, const float* __restrict__ alpha,
                       const float* __restrict__ beta, float* __restrict__ out) {
  __shared__ float XsT[768 * 12];  // [k][r] stride 12
  int t = threadIdx.x;
  int c0 = blockIdx.x * 64, r0 = blockIdx.y * 8;
#pragma unroll
  for (int j = 0; j < 3; ++j) {
    int fidx = j * 512 + t;  // 0..1535
    int r = fidx / 192, c4 = fidx % 192;
    float4 v = *(const float4*)(X + (size_t)(r0 + r) * 768 + c4 * 4);
    int kb = c4 * 4;
    XsT[(kb + 0) * 12 + r] = v.x;
    XsT[(kb + 1) * 12 + r] = v.y;
    XsT[(kb + 2) * 12 + r] = v.z;
    XsT[(kb + 3) * 12 + r] = v.w;
  }
  __syncthreads();
  if (LN) {
    int w = t >> 6, l = t & 63;  // 8 waves, one row each
    float s = 0.f, ss = 0.f;
#pragma unroll
    for (int m = 0; m < 12; ++m) {
      float x = XsT[(l + 64 * m) * 12 + w];
      s += x; ss += x * x;
    }
#pragma unroll
    for (int o = 32; o; o >>= 1) { s += __shfl_xor(s, o); ss += __shfl_xor(ss, o); }
    float mu = s * (1.f / 768.f), rs = rsqrtf(ss * (1.f / 768.f) - mu * mu + LNEPS);
#pragma unroll
    for (int m = 0; m < 12; ++m) {
      int d = l + 64 * m;
      XsT[d * 12 + w] = (XsT[d * 12 + w] - mu) * rs * gamma[d] + beta_ln[d];
    }
    __syncthreads();
  }
  int cx = t & 63, kg = t >> 6;
  int c = c0 + cx;
  float acc[8] = {};
  const float* wp = W + c;
  int k0 = kg * 96;
#pragma unroll 8
  for (int k = k0; k < k0 + 96; ++k) {
    float wv = wp[(size_t)k * 768];
    float4 xa = *(const float4*)&XsT[k * 12];
    float4 xb = *(const float4*)&XsT[k * 12 + 4];
    acc[0] += xa.x * wv; acc[1] += xa.y * wv; acc[2] += xa.z * wv; acc[3] += xa.w * wv;
    acc[4] += xb.x * wv; acc[5] += xb.y * wv; acc[6] += xb.z * wv; acc[7] += xb.w * wv;
  }
  __syncthreads();  // done reading XsT; reuse as reduce buffer
  float* red = XsT;
  if (kg > 0) {
#pragma unroll
    for (int r = 0; r < 8; ++r) red[((kg - 1) * 8 + r) * 64 + cx] = acc[r];
  }
  __syncthreads();
  if (kg == 0) {
#pragma unroll
    for (int g = 1; g < 8; ++g)
#pragma unroll
      for (int r = 0; r < 8; ++r) acc[r] += red[((g - 1) * 8 + r) * 64 + cx];
    float bsc = (MODE == 1) ? 0.f : bias[c];
#pragma unroll
    for (int r = 0; r < 8; ++r) {
      int rr = r0 + r;
      size_t oidx = (size_t)rr * 768 + c;
      float v;
      if (MODE == 0) v = acc[r] + bsc;
      else if (MODE == 1) v = acc[r];
      else if (MODE == 2) v = acc[r] * alpha[rr] + bsc * beta[rr];
      else if (MODE == 3) v = fmaxf(acc[r] + bsc, 0.f);
      else v = out[oidx] + acc[r] + bsc;
      out[oidx] = v;
    }
  }
}

// ---------------- per-slot scalars: Sq = qk.g_in ; c0 = qk.b_in + q.bk ----------------
__global__ void qprep_k(const float* __restrict__ q, const float* __restrict__ qk,
                        const float* __restrict__ g_in, const float* __restrict__ b_in,
                        const float* __restrict__ bk, float* __restrict__ Sqbuf,
                        float* __restrict__ c0buf) {
  int row = blockIdx.x * 4 + (threadIdx.x >> 6), l = threadIdx.x & 63;
  float aS = 0.f, aC = 0.f;
#pragma unroll
  for (int j = 0; j < 12; ++j) {
    int d = l + 64 * j;
    float qkv = qk[(size_t)row * 768 + d];
    aS += qkv * g_in[d];
    aC += qkv * b_in[d] + q[(size_t)row * 768 + d] * bk[d];
  }
#pragma unroll
  for (int o = 32; o; o >>= 1) { aS += __shfl_xor(aS, o); aC += __shfl_xor(aC, o); }
  if (l == 0) { Sqbuf[row] = aS; c0buf[row] = aC; }
}

// ---------------- FUSED dots+softmax+pool, x staged in LDS (2 subtiles x 32 rows) -------
// grid (16 chunk, 32 b), 512 thr. xt stride 392 (16B-aligned rows; adjacent-row groups at
// bank offsets {0,8,16,24} -> 2-way = free). Dots: 32-lane row-groups (2/wave, 2 passes),
// f32x2 pk-FMA. Pool: f32x2 acc + f32x2 ow reads. FIRST folds fp32->bf16 cast.
template <bool FIRST>
__global__ void __launch_bounds__(512, 2)
dotspool_k(const float* __restrict__ inf, uint32* __restrict__ xh,
           const float* __restrict__ qk, const float* __restrict__ g_in,
           const float* __restrict__ Sqbuf, const float* __restrict__ c0buf,
           float* __restrict__ attnbuf, float* __restrict__ partials,
           float* __restrict__ A0p, float* __restrict__ A1p) {
  __shared__ float qkgs[8][768];
  __shared__ uint32 xt[32 * 392];
  __shared__ float oa[64][8], ow[64][8], orm[64];
  __shared__ float c0s[8], Sqs[8];
  int chunk = blockIdx.x, b = blockIdx.y, t = threadIdx.x, w = t >> 6, l = t & 63;
  for (int i = t; i < 6144; i += 512)
    ((float*)qkgs)[i] = qk[(size_t)b * 6144 + i] * g_in[i % 768];
  if (t < 8) { c0s[t] = c0buf[b * 8 + t]; Sqs[t] = Sqbuf[b * 8 + t]; }
  int g32 = l & 31, grp = l >> 5;  // 32-lane row groups, 2 per wave
  f32x2 pacc[8] = {};
#pragma unroll
  for (int sub = 0; sub < 2; ++sub) {
    if (FIRST) {
      const float4* xpf =
          (const float4*)(inf + ((size_t)b * 1024 + chunk * 64 + sub * 32) * 768);
      uint2* xg = (uint2*)(xh + ((size_t)b * 1024 + chunk * 64 + sub * 32) * 384);
#pragma unroll
      for (int j = 0; j < 12; ++j) {
        int idx = j * 512 + t;  // 6144 float4s
        int row = idx / 192, c4 = idx % 192;
        float4 v = xpf[(size_t)row * 192 + c4];
        uint2 o;
        o.x = bfb(v.x) | (bfb(v.y) << 16);
        o.y = bfb(v.z) | (bfb(v.w) << 16);
        *(uint2*)&xt[row * 392 + c4 * 2] = o;
        xg[(size_t)row * 192 + c4] = o;
      }
    } else {
      const uint4* xps4 = (const uint4*)(xh + ((size_t)b * 1024 + chunk * 64) * 384 +
                                         sub * 12288);
#pragma unroll
      for (int j = 0; j < 6; ++j) {
        int idx = j * 512 + t;  // 3072 uint4s
        int row = idx / 96, c4 = idx % 96;
        *(uint4*)&xt[row * 392 + c4 * 4] = xps4[idx];
      }
    }
    __syncthreads();
    // dots+softmax: 16 groups x 32 lanes, 2 passes of 16 rows
#pragma unroll
    for (int rr = 0; rr < 2; ++rr) {
      int lr32 = rr * 16 + w * 2 + grp;  // 0..31
      int lr = sub * 32 + lr32;
      const uint32* xr = &xt[lr32 * 392];
      f32x2 sv = {0.f, 0.f}, ssv = {0.f, 0.f};
      f32x2 ds2[8] = {};
#pragma unroll 4
      for (int j = 0; j < 12; ++j) {
        uint32 u = xr[j * 32 + g32];
        f32x2 ab;
        ab.x = __uint_as_float(u << 16);
        ab.y = __uint_as_float(u & 0xffff0000u);
        sv += ab;
        ssv += ab * ab;
        int d0 = 2 * (j * 32 + g32);
#pragma unroll
        for (int s2 = 0; s2 < 8; ++s2) {
          f32x2 qg = *(const f32x2*)&qkgs[s2][d0];
          ds2[s2] += qg * ab;
        }
      }
      float s = sv.x + sv.y, ss = ssv.x + ssv.y;
      float ds[8];
#pragma unroll
      for (int s2 = 0; s2 < 8; ++s2) ds[s2] = ds2[s2].x + ds2[s2].y;
#pragma unroll
      for (int o = 1; o < 32; o <<= 1) {
        s += __shfl_xor(s, o);
        ss += __shfl_xor(ss, o);
#pragma unroll
        for (int s2 = 0; s2 < 8; ++s2) ds[s2] += __shfl_xor(ds[s2], o);
      }
      float mu = s * (1.f / 768.f), r = rsqrtf(ss * (1.f / 768.f) - mu * mu + LNEPS);
      float rmu = r * mu;
      float sc[8];
#pragma unroll
      for (int s2 = 0; s2 < 8; ++s2)
        sc[s2] = (r * ds[s2] - rmu * Sqs[s2] + c0s[s2]) * SCALE_Q;
      float mx = sc[0];
#pragma unroll
      for (int s2 = 1; s2 < 8; ++s2) mx = fmaxf(mx, sc[s2]);
      float e[8], se = 0.f;
#pragma unroll
      for (int s2 = 0; s2 < 8; ++s2) { e[s2] = __expf(sc[s2] - mx); se += e[s2]; }
      float inv_se = 1.f / se;
      float av = e[0];
#pragma unroll
      for (int s2 = 1; s2 < 8; ++s2) av = (g32 == s2) ? e[s2] : av;
      av *= inv_se;
      if (g32 < 8) {
        oa[lr][g32] = av;
        ow[lr][g32] = av * r;
      }
      if (g32 == 8) orm[lr] = rmu;
    }
    __syncthreads();
    // pool this subtile from LDS (threads 0..383 own one packed col)
    if (t < 384) {
#pragma unroll 2
      for (int nn = 0; nn < 32; ++nn) {
        uint32 u = xt[nn * 392 + t];
        f32x2 xv;
        xv.x = __uint_as_float(u << 16);
        xv.y = __uint_as_float(u & 0xffff0000u);
        const float* owr = &ow[sub * 32 + nn][0];
#pragma unroll
        for (int k = 0; k < 4; ++k) {
          f32x2 owv = *(const f32x2*)&owr[2 * k];
          pacc[2 * k] += owv.x * xv;
          pacc[2 * k + 1] += owv.y * xv;
        }
      }
    } else if (sub == 1 && t < 392) {
      int sl = t - 384;
      float A0 = 0.f, A1 = 0.f;
      for (int rr2 = 0; rr2 < 64; ++rr2) {
        float a = oa[rr2][sl];
        A0 += a;
        A1 += a * orm[rr2];
      }
      A0p[chunk * 256 + b * 8 + sl] = A0;
      A1p[chunk * 256 + b * 8 + sl] = A1;
    }
    __syncthreads();
  }
  if (t < 384) {
#pragma unroll
    for (int s2 = 0; s2 < 8; ++s2) {
      size_t base = ((size_t)(chunk * 256 + b * 8 + s2)) * 768;
      *(f32x2*)&partials[base + 2 * t] = pacc[s2];
    }
  }
  size_t base8 = ((size_t)b * 1024 + chunk * 64) * 8;
  attnbuf[base8 + t] = oa[t >> 3][t & 7];
}

// ---------------- reduce partials + A0/A1 + LN-fixup -> pooled ; inv, rho ----------------
__global__ void reduce_fix_k(const float* __restrict__ partials, const float* __restrict__ A0p,
                             const float* __restrict__ A1p, const float* __restrict__ g_in,
                             const float* __restrict__ b_in, float* __restrict__ pooled,
                             float* __restrict__ invbuf, float* __restrict__ rhobuf) {
  int row = blockIdx.x, t = threadIdx.x;  // row = b*8+s
  float A0 = 0.f, A1 = 0.f;
#pragma unroll
  for (int ch = 0; ch < 16; ++ch) {
    A0 += A0p[ch * 256 + row];
    A1 += A1p[ch * 256 + row];
  }
#pragma unroll
  for (int c = 0; c < 3; ++c) {
    int d = t + 256 * c;
    float a = 0.f;
    for (int ch = 0; ch < 16; ++ch) a += partials[((size_t)(ch * 256 + row)) * 768 + d];
    pooled[(size_t)row * 768 + d] = g_in[d] * (a - A1) + b_in[d] * A0;
  }
  if (t == 0) {
    float iv = 1.f / (A0 + AEPS);
    invbuf[row] = iv;
    rhobuf[row] = A0 * iv;
  }
}

// ---------------- merged output writer (fp32) ----------------
__global__ void outs_k(const float* __restrict__ slots, const float* __restrict__ attnbuf,
                       const float* __restrict__ invbuf, float* __restrict__ out) {
  int i = blockIdx.x * 256 + threadIdx.x;  // 458752
  if (i < 196608) {
    out[i] = slots[i];
  } else {
    int j = i - 196608;  // [b][n][s]
    out[i] = attnbuf[j] * invbuf[((j >> 13) << 3) + (j & 7)];
  }
}

extern "C" void kernel_launch(void* const* d_in, const int* in_sizes, int n_in,
                              void* d_out, int out_size, void* d_ws, size_t ws_size,
                              hipStream_t stream) {
  (void)in_sizes; (void)n_in; (void)out_size; (void)ws_size;
  const float* slots0 = (const float*)d_in[0];
  const float* inputs = (const float*)d_in[1];
  const float* Wq = (const float*)d_in[2];
  const float* bq = (const float*)d_in[3];
  const float* Wk = (const float*)d_in[4];
  const float* bk = (const float*)d_in[5];
  const float* Wv = (const float*)d_in[6];
  const float* bv = (const float*)d_in[7];
  const float* g_in = (const float*)d_in[8];
  const float* b_in = (const float*)d_in[9];
  const float* g_s = (const float*)d_in[10];
  const float* b_s = (const float*)d_in[11];
  const float* g_ff = (const float*)d_in[12];
  const float* b_ff = (const float*)d_in[13];
  const float* W1 = (const float*)d_in[14];
  const float* b1 = (const float*)d_in[15];
  const float* W2 = (const float*)d_in[16];
  const float* b2 = (const float*)d_in[17];

  char* p = (char*)d_ws;
  uint32* xh = (uint32*)p;     p += (size_t)32768 * 384 * 4;  // packed bf16 inputs
  float* WkT = (float*)p;      p += (size_t)768 * 768 * 4;
  float* slotsf = (float*)p;   p += 256 * 768 * 4;
  float* qbuf = (float*)p;     p += 256 * 768 * 4;
  float* qkbuf = (float*)p;    p += 256 * 768 * 4;
  float* Sqbuf = (float*)p;    p += 256 * 4;
  float* c0buf = (float*)p;    p += 256 * 4;
  float* attnbuf = (float*)p;  p += (size_t)32768 * 8 * 4;
  float* partials = (float*)p; p += (size_t)16 * 256 * 768 * 4;
  float* A0p = (float*)p;      p += 16 * 256 * 4;
  float* A1p = (float*)p;      p += 16 * 256 * 4;
  float* pooled = (float*)p;   p += 256 * 768 * 4;
  float* invbuf = (float*)p;   p += 256 * 4;
  float* rhobuf = (float*)p;   p += 256 * 4;
  float* updbuf = (float*)p;   p += 256 * 768 * 4;
  float* t1buf = (float*)p;    p += 256 * 768 * 4;

  dim3 ggrid(12, 32);
  setup_k<<<1344, 256, 0, stream>>>(Wk, WkT, slots0, slotsf);
  for (int it = 0; it < 3; ++it) {
    gemv_k<true, 0><<<ggrid, 512, 0, stream>>>(slotsf, Wq, bq, g_s, b_s, nullptr, nullptr,
                                               qbuf);
    gemv_k<false, 1><<<ggrid, 512, 0, stream>>>(qbuf, WkT, nullptr, nullptr, nullptr, nullptr,
                                                nullptr, qkbuf);
    qprep_k<<<64, 256, 0, stream>>>(qbuf, qkbuf, g_in, b_in, bk, Sqbuf, c0buf);
    if (it == 0)
      dotspool_k<true><<<dim3(16, 32), 512, 0, stream>>>(inputs, xh, qkbuf, g_in, Sqbuf,
                                                         c0buf, attnbuf, partials, A0p, A1p);
    else
      dotspool_k<false><<<dim3(16, 32), 512, 0, stream>>>(inputs, xh, qkbuf, g_in, Sqbuf,
                                                          c0buf, attnbuf, partials, A0p, A1p);
    reduce_fix_k<<<256, 256, 0, stream>>>(partials, A0p, A1p, g_in, b_in, pooled,
                                          invbuf, rhobuf);
    gemv_k<false, 2><<<ggrid, 512, 0, stream>>>(pooled, Wv, bv, nullptr, nullptr, invbuf,
                                                rhobuf, updbuf);
    gemv_k<true, 3><<<ggrid, 512, 0, stream>>>(updbuf, W1, b1, g_ff, b_ff, nullptr, nullptr,
                                               t1buf);
    gemv_k<false, 4><<<ggrid, 512, 0, stream>>>(t1buf, W2, b2, nullptr, nullptr, nullptr,
                                                nullptr, slotsf);
  }
  outs_k<<<1792, 256, 0, stream>>>(slotsf, attnbuf, invbuf, (float*)d_out);
}

// Round 18
// 338.895 us; speedup vs baseline: 1.0341x; 1.0341x over previous
//
#include <hip/hip_runtime.h>

#define LNEPS 1e-5f
#define AEPS 1e-8f
#define SCALE_Q 0.036084391824351615f  // 768^-0.5

typedef unsigned int uint32;
typedef float f32x2 __attribute__((ext_vector_type(2)));

__device__ inline uint32 bfb(float f) {
  __bf16 h = (__bf16)f;
  unsigned short u;
  __builtin_memcpy(&u, &h, 2);
  return (uint32)u;
}
__device__ inline f32x2 unpk(uint32 u) {
  f32x2 v;
  v.x = __uint_as_float(u << 16);
  v.y = __uint_as_float(u & 0xffff0000u);
  return v;
}

// ---------------- one-time setup: packT Wk | init slots ----------------
__global__ void setup_k(const float* __restrict__ Wk, float* __restrict__ WkT,
                        const float* __restrict__ s0, float* __restrict__ slots) {
  __shared__ float tile[32][33];
  int bb = blockIdx.x, t = threadIdx.x;
  if (bb < 576) {
    int c0 = (bb % 24) * 32, i0 = (bb / 24) * 32;
    int tx = t & 31, ty = t >> 5;
#pragma unroll
    for (int k = 0; k < 4; ++k)
      tile[ty + 8 * k][tx] = Wk[(size_t)(i0 + ty + 8 * k) * 768 + c0 + tx];
    __syncthreads();
#pragma unroll
    for (int k = 0; k < 4; ++k)
      WkT[(size_t)(c0 + ty + 8 * k) * 768 + i0 + tx] = tile[tx][ty + 8 * k];
  } else {
    int idx = (bb - 576) * 256 + t;  // 196608
    slots[idx] = s0[idx % 6144];
  }
}

// ---------------- batched GEMV v3: 64 cols/block, 8-way k-split, 512 thr, grid (12,32) ----
// MODE 0: acc+bias | 1: acc | 2: alpha[r]*acc+beta[r]*bias | 3: relu(acc+bias) | 4: out+=acc+bias
template <bool LN, int MODE>
__global__ void gemv_k(const float* __restrict__ X, const float* __restrict__ W,
                       const float* __restrict__ bias, const float* __restrict__ gamma,
                       const float* __restrict__ beta_ln, const float* __restrict__ alpha,
                       const float* __restrict__ beta, float* __restrict__ out) {
  __shared__ float XsT[768 * 12];  // [k][r] stride 12
  int t = threadIdx.x;
  int c0 = blockIdx.x * 64, r0 = blockIdx.y * 8;
#pragma unroll
  for (int j = 0; j < 3; ++j) {
    int fidx = j * 512 + t;  // 0..1535
    int r = fidx / 192, c4 = fidx % 192;
    float4 v = *(const float4*)(X + (size_t)(r0 + r) * 768 + c4 * 4);
    int kb = c4 * 4;
    XsT[(kb + 0) * 12 + r] = v.x;
    XsT[(kb + 1) * 12 + r] = v.y;
    XsT[(kb + 2) * 12 + r] = v.z;
    XsT[(kb + 3) * 12 + r] = v.w;
  }
  __syncthreads();
  if (LN) {
    int w = t >> 6, l = t & 63;  // 8 waves, one row each
    float s = 0.f, ss = 0.f;
#pragma unroll
    for (int m = 0; m < 12; ++m) {
      float x = XsT[(l + 64 * m) * 12 + w];
      s += x; ss += x * x;
    }
#pragma unroll
    for (int o = 32; o; o >>= 1) { s += __shfl_xor(s, o); ss += __shfl_xor(ss, o); }
    float mu = s * (1.f / 768.f), rs = rsqrtf(ss * (1.f / 768.f) - mu * mu + LNEPS);
#pragma unroll
    for (int m = 0; m < 12; ++m) {
      int d = l + 64 * m;
      XsT[d * 12 + w] = (XsT[d * 12 + w] - mu) * rs * gamma[d] + beta_ln[d];
    }
    __syncthreads();
  }
  int cx = t & 63, kg = t >> 6;
  int c = c0 + cx;
  float acc[8] = {};
  const float* wp = W + c;
  int k0 = kg * 96;
#pragma unroll 8
  for (int k = k0; k < k0 + 96; ++k) {
    float wv = wp[(size_t)k * 768];
    float4 xa = *(const float4*)&XsT[k * 12];
    float4 xb = *(const float4*)&XsT[k * 12 + 4];
    acc[0] += xa.x * wv; acc[1] += xa.y * wv; acc[2] += xa.z * wv; acc[3] += xa.w * wv;
    acc[4] += xb.x * wv; acc[5] += xb.y * wv; acc[6] += xb.z * wv; acc[7] += xb.w * wv;
  }
  __syncthreads();  // done reading XsT; reuse as reduce buffer
  float* red = XsT;
  if (kg > 0) {
#pragma unroll
    for (int r = 0; r < 8; ++r) red[((kg - 1) * 8 + r) * 64 + cx] = acc[r];
  }
  __syncthreads();
  if (kg == 0) {
#pragma unroll
    for (int g = 1; g < 8; ++g)
#pragma unroll
      for (int r = 0; r < 8; ++r) acc[r] += red[((g - 1) * 8 + r) * 64 + cx];
    float bsc = (MODE == 1) ? 0.f : bias[c];
#pragma unroll
    for (int r = 0; r < 8; ++r) {
      int rr = r0 + r;
      size_t oidx = (size_t)rr * 768 + c;
      float v;
      if (MODE == 0) v = acc[r] + bsc;
      else if (MODE == 1) v = acc[r];
      else if (MODE == 2) v = acc[r] * alpha[rr] + bsc * beta[rr];
      else if (MODE == 3) v = fmaxf(acc[r] + bsc, 0.f);
      else v = out[oidx] + acc[r] + bsc;
      out[oidx] = v;
    }
  }
}

// ---------------- per-slot scalars: Sq = qk.g_in ; c0 = qk.b_in + q.bk ----------------
__global__ void qprep_k(const float* __restrict__ q, const float* __restrict__ qk,
                        const float* __restrict__ g_in, const float* __restrict__ b_in,
                        const float* __restrict__ bk, float* __restrict__ Sqbuf,
                        float* __restrict__ c0buf) {
  int row = blockIdx.x * 4 + (threadIdx.x >> 6), l = threadIdx.x & 63;
  float aS = 0.f, aC = 0.f;
#pragma unroll
  for (int j = 0; j < 12; ++j) {
    int d = l + 64 * j;
    float qkv = qk[(size_t)row * 768 + d];
    aS += qkv * g_in[d];
    aC += qkv * b_in[d] + q[(size_t)row * 768 + d] * bk[d];
  }
#pragma unroll
  for (int o = 32; o; o >>= 1) { aS += __shfl_xor(aS, o); aC += __shfl_xor(aC, o); }
  if (l == 0) { Sqbuf[row] = aS; c0buf[row] = aC; }
}

// ---------------- FUSED dots+softmax+pool, x staged in LDS (2 subtiles x 32 rows) -------
// grid (16 chunk, 32 b), 512 thr. xt stride 392 (conflict-free, r17-verified).
// Partials emitted as PACKED bf16 pairs (uint per 2 d) -> halves partials traffic.
template <bool FIRST>
__global__ void __launch_bounds__(512, 2)
dotspool_k(const float* __restrict__ inf, uint32* __restrict__ xh,
           const float* __restrict__ qk, const float* __restrict__ g_in,
           const float* __restrict__ Sqbuf, const float* __restrict__ c0buf,
           float* __restrict__ attnbuf, uint32* __restrict__ partials,
           float* __restrict__ A0p, float* __restrict__ A1p) {
  __shared__ float qkgs[8][768];
  __shared__ uint32 xt[32 * 392];
  __shared__ float oa[64][8], ow[64][8], orm[64];
  __shared__ float c0s[8], Sqs[8];
  int chunk = blockIdx.x, b = blockIdx.y, t = threadIdx.x, w = t >> 6, l = t & 63;
  for (int i = t; i < 6144; i += 512)
    ((float*)qkgs)[i] = qk[(size_t)b * 6144 + i] * g_in[i % 768];
  if (t < 8) { c0s[t] = c0buf[b * 8 + t]; Sqs[t] = Sqbuf[b * 8 + t]; }
  int g32 = l & 31, grp = l >> 5;  // 32-lane row groups, 2 per wave
  f32x2 pacc[8] = {};
#pragma unroll
  for (int sub = 0; sub < 2; ++sub) {
    if (FIRST) {
      const float4* xpf =
          (const float4*)(inf + ((size_t)b * 1024 + chunk * 64 + sub * 32) * 768);
      uint2* xg = (uint2*)(xh + ((size_t)b * 1024 + chunk * 64 + sub * 32) * 384);
#pragma unroll
      for (int j = 0; j < 12; ++j) {
        int idx = j * 512 + t;  // 6144 float4s
        int row = idx / 192, c4 = idx % 192;
        float4 v = xpf[(size_t)row * 192 + c4];
        uint2 o;
        o.x = bfb(v.x) | (bfb(v.y) << 16);
        o.y = bfb(v.z) | (bfb(v.w) << 16);
        *(uint2*)&xt[row * 392 + c4 * 2] = o;
        xg[(size_t)row * 192 + c4] = o;
      }
    } else {
      const uint4* xps4 = (const uint4*)(xh + ((size_t)b * 1024 + chunk * 64) * 384 +
                                         sub * 12288);
#pragma unroll
      for (int j = 0; j < 6; ++j) {
        int idx = j * 512 + t;  // 3072 uint4s
        int row = idx / 96, c4 = idx % 96;
        *(uint4*)&xt[row * 392 + c4 * 4] = xps4[idx];
      }
    }
    __syncthreads();
    // dots+softmax: 16 groups x 32 lanes, 2 passes of 16 rows
#pragma unroll
    for (int rr = 0; rr < 2; ++rr) {
      int lr32 = rr * 16 + w * 2 + grp;  // 0..31
      int lr = sub * 32 + lr32;
      const uint32* xr = &xt[lr32 * 392];
      f32x2 sv = {0.f, 0.f}, ssv = {0.f, 0.f};
      f32x2 ds2[8] = {};
#pragma unroll 4
      for (int j = 0; j < 12; ++j) {
        uint32 u = xr[j * 32 + g32];
        f32x2 ab = unpk(u);
        sv += ab;
        ssv += ab * ab;
        int d0 = 2 * (j * 32 + g32);
#pragma unroll
        for (int s2 = 0; s2 < 8; ++s2) {
          f32x2 qg = *(const f32x2*)&qkgs[s2][d0];
          ds2[s2] += qg * ab;
        }
      }
      float s = sv.x + sv.y, ss = ssv.x + ssv.y;
      float ds[8];
#pragma unroll
      for (int s2 = 0; s2 < 8; ++s2) ds[s2] = ds2[s2].x + ds2[s2].y;
#pragma unroll
      for (int o = 1; o < 32; o <<= 1) {
        s += __shfl_xor(s, o);
        ss += __shfl_xor(ss, o);
#pragma unroll
        for (int s2 = 0; s2 < 8; ++s2) ds[s2] += __shfl_xor(ds[s2], o);
      }
      float mu = s * (1.f / 768.f), r = rsqrtf(ss * (1.f / 768.f) - mu * mu + LNEPS);
      float rmu = r * mu;
      float sc[8];
#pragma unroll
      for (int s2 = 0; s2 < 8; ++s2)
        sc[s2] = (r * ds[s2] - rmu * Sqs[s2] + c0s[s2]) * SCALE_Q;
      float mx = sc[0];
#pragma unroll
      for (int s2 = 1; s2 < 8; ++s2) mx = fmaxf(mx, sc[s2]);
      float e[8], se = 0.f;
#pragma unroll
      for (int s2 = 0; s2 < 8; ++s2) { e[s2] = __expf(sc[s2] - mx); se += e[s2]; }
      float inv_se = 1.f / se;
      float av = e[0];
#pragma unroll
      for (int s2 = 1; s2 < 8; ++s2) av = (g32 == s2) ? e[s2] : av;
      av *= inv_se;
      if (g32 < 8) {
        oa[lr][g32] = av;
        ow[lr][g32] = av * r;
      }
      if (g32 == 8) orm[lr] = rmu;
    }
    __syncthreads();
    // pool this subtile from LDS (threads 0..383 own one packed col)
    if (t < 384) {
#pragma unroll 2
      for (int nn = 0; nn < 32; ++nn) {
        f32x2 xv = unpk(xt[nn * 392 + t]);
        const float* owr = &ow[sub * 32 + nn][0];
#pragma unroll
        for (int k = 0; k < 4; ++k) {
          f32x2 owv = *(const f32x2*)&owr[2 * k];
          pacc[2 * k] += owv.x * xv;
          pacc[2 * k + 1] += owv.y * xv;
        }
      }
    } else if (sub == 1 && t < 392) {
      int sl = t - 384;
      float A0 = 0.f, A1 = 0.f;
      for (int rr2 = 0; rr2 < 64; ++rr2) {
        float a = oa[rr2][sl];
        A0 += a;
        A1 += a * orm[rr2];
      }
      A0p[chunk * 256 + b * 8 + sl] = A0;
      A1p[chunk * 256 + b * 8 + sl] = A1;
    }
    __syncthreads();
  }
  if (t < 384) {
#pragma unroll
    for (int s2 = 0; s2 < 8; ++s2) {
      size_t base = ((size_t)(chunk * 256 + b * 8 + s2)) * 384;
      partials[base + t] = bfb(pacc[s2].x) | (bfb(pacc[s2].y) << 16);
    }
  }
  size_t base8 = ((size_t)b * 1024 + chunk * 64) * 8;
  attnbuf[base8 + t] = oa[t >> 3][t & 7];
}

// ---------------- reduce packed partials + A0/A1 + LN-fixup -> pooled ; inv, rho --------
// grid 256 (row = b*8+s), 384 thr (one d-pair each)
__global__ void reduce_fix_k(const uint32* __restrict__ partials, const float* __restrict__ A0p,
                             const float* __restrict__ A1p, const float* __restrict__ g_in,
                             const float* __restrict__ b_in, float* __restrict__ pooled,
                             float* __restrict__ invbuf, float* __restrict__ rhobuf) {
  int row = blockIdx.x, t = threadIdx.x;  // row = b*8+s ; t = d-pair index
  float A0 = 0.f, A1 = 0.f;
#pragma unroll
  for (int ch = 0; ch < 16; ++ch) {
    A0 += A0p[ch * 256 + row];
    A1 += A1p[ch * 256 + row];
  }
  f32x2 a = {0.f, 0.f};
#pragma unroll
  for (int ch = 0; ch < 16; ++ch)
    a += unpk(partials[((size_t)(ch * 256 + row)) * 384 + t]);
  int d = 2 * t;
  f32x2 g = *(const f32x2*)&g_in[d];
  f32x2 bi = *(const f32x2*)&b_in[d];
  f32x2 res;
  res.x = g.x * (a.x - A1) + bi.x * A0;
  res.y = g.y * (a.y - A1) + bi.y * A0;
  *(f32x2*)&pooled[(size_t)row * 768 + d] = res;
  if (t == 0) {
    float iv = 1.f / (A0 + AEPS);
    invbuf[row] = iv;
    rhobuf[row] = A0 * iv;
  }
}

// ---------------- merged output writer (fp32) ----------------
__global__ void outs_k(const float* __restrict__ slots, const float* __restrict__ attnbuf,
                       const float* __restrict__ invbuf, float* __restrict__ out) {
  int i = blockIdx.x * 256 + threadIdx.x;  // 458752
  if (i < 196608) {
    out[i] = slots[i];
  } else {
    int j = i - 196608;  // [b][n][s]
    out[i] = attnbuf[j] * invbuf[((j >> 13) << 3) + (j & 7)];
  }
}

extern "C" void kernel_launch(void* const* d_in, const int* in_sizes, int n_in,
                              void* d_out, int out_size, void* d_ws, size_t ws_size,
                              hipStream_t stream) {
  (void)in_sizes; (void)n_in; (void)out_size; (void)ws_size;
  const float* slots0 = (const float*)d_in[0];
  const float* inputs = (const float*)d_in[1];
  const float* Wq = (const float*)d_in[2];
  const float* bq = (const float*)d_in[3];
  const float* Wk = (const float*)d_in[4];
  const float* bk = (const float*)d_in[5];
  const float* Wv = (const float*)d_in[6];
  const float* bv = (const float*)d_in[7];
  const float* g_in = (const float*)d_in[8];
  const float* b_in = (const float*)d_in[9];
  const float* g_s = (const float*)d_in[10];
  const float* b_s = (const float*)d_in[11];
  const float* g_ff = (const float*)d_in[12];
  const float* b_ff = (const float*)d_in[13];
  const float* W1 = (const float*)d_in[14];
  const float* b1 = (const float*)d_in[15];
  const float* W2 = (const float*)d_in[16];
  const float* b2 = (const float*)d_in[17];

  char* p = (char*)d_ws;
  uint32* xh = (uint32*)p;     p += (size_t)32768 * 384 * 4;  // packed bf16 inputs
  float* WkT = (float*)p;      p += (size_t)768 * 768 * 4;
  float* slotsf = (float*)p;   p += 256 * 768 * 4;
  float* qbuf = (float*)p;     p += 256 * 768 * 4;
  float* qkbuf = (float*)p;    p += 256 * 768 * 4;
  float* Sqbuf = (float*)p;    p += 256 * 4;
  float* c0buf = (float*)p;    p += 256 * 4;
  float* attnbuf = (float*)p;  p += (size_t)32768 * 8 * 4;
  uint32* partials = (uint32*)p; p += (size_t)16 * 256 * 384 * 4;  // packed bf16 pairs
  float* A0p = (float*)p;      p += 16 * 256 * 4;
  float* A1p = (float*)p;      p += 16 * 256 * 4;
  float* pooled = (float*)p;   p += 256 * 768 * 4;
  float* invbuf = (float*)p;   p += 256 * 4;
  float* rhobuf = (float*)p;   p += 256 * 4;
  float* updbuf = (float*)p;   p += 256 * 768 * 4;
  float* t1buf = (float*)p;    p += 256 * 768 * 4;

  dim3 ggrid(12, 32);
  setup_k<<<1344, 256, 0, stream>>>(Wk, WkT, slots0, slotsf);
  for (int it = 0; it < 3; ++it) {
    gemv_k<true, 0><<<ggrid, 512, 0, stream>>>(slotsf, Wq, bq, g_s, b_s, nullptr, nullptr,
                                               qbuf);
    gemv_k<false, 1><<<ggrid, 512, 0, stream>>>(qbuf, WkT, nullptr, nullptr, nullptr, nullptr,
                                                nullptr, qkbuf);
    qprep_k<<<64, 256, 0, stream>>>(qbuf, qkbuf, g_in, b_in, bk, Sqbuf, c0buf);
    if (it == 0)
      dotspool_k<true><<<dim3(16, 32), 512, 0, stream>>>(inputs, xh, qkbuf, g_in, Sqbuf,
                                                         c0buf, attnbuf, partials, A0p, A1p);
    else
      dotspool_k<false><<<dim3(16, 32), 512, 0, stream>>>(inputs, xh, qkbuf, g_in, Sqbuf,
                                                          c0buf, attnbuf, partials, A0p, A1p);
    reduce_fix_k<<<256, 384, 0, stream>>>(partials, A0p, A1p, g_in, b_in, pooled,
                                          invbuf, rhobuf);
    gemv_k<false, 2><<<ggrid, 512, 0, stream>>>(pooled, Wv, bv, nullptr, nullptr, invbuf,
                                                rhobuf, updbuf);
    gemv_k<true, 3><<<ggrid, 512, 0, stream>>>(updbuf, W1, b1, g_ff, b_ff, nullptr, nullptr,
                                               t1buf);
    gemv_k<false, 4><<<ggrid, 512, 0, stream>>>(t1buf, W2, b2, nullptr, nullptr, nullptr,
                                                nullptr, slotsf);
  }
  outs_k<<<1792, 256, 0, stream>>>(slotsf, attnbuf, invbuf, (float*)d_out);
}

// Round 19
// 331.406 us; speedup vs baseline: 1.0575x; 1.0226x over previous
//
#include <hip/hip_runtime.h>

#define LNEPS 1e-5f
#define AEPS 1e-8f
#define SCALE_Q 0.036084391824351615f  // 768^-0.5

typedef unsigned int uint32;
typedef float f32x2 __attribute__((ext_vector_type(2)));

__device__ inline uint32 bfb(float f) {
  __bf16 h = (__bf16)f;
  unsigned short u;
  __builtin_memcpy(&u, &h, 2);
  return (uint32)u;
}
__device__ inline f32x2 unpk(uint32 u) {
  f32x2 v;
  v.x = __uint_as_float(u << 16);
  v.y = __uint_as_float(u & 0xffff0000u);
  return v;
}

// ---------------- one-time setup: packT Wk | init slots ----------------
__global__ void setup_k(const float* __restrict__ Wk, float* __restrict__ WkT,
                        const float* __restrict__ s0, float* __restrict__ slots) {
  __shared__ float tile[32][33];
  int bb = blockIdx.x, t = threadIdx.x;
  if (bb < 576) {
    int c0 = (bb % 24) * 32, i0 = (bb / 24) * 32;
    int tx = t & 31, ty = t >> 5;
#pragma unroll
    for (int k = 0; k < 4; ++k)
      tile[ty + 8 * k][tx] = Wk[(size_t)(i0 + ty + 8 * k) * 768 + c0 + tx];
    __syncthreads();
#pragma unroll
    for (int k = 0; k < 4; ++k)
      WkT[(size_t)(c0 + ty + 8 * k) * 768 + i0 + tx] = tile[tx][ty + 8 * k];
  } else {
    int idx = (bb - 576) * 256 + t;  // 196608
    slots[idx] = s0[idx % 6144];
  }
}

// ---------------- batched GEMV v3: 64 cols/block, 8-way k-split, 512 thr, grid (12,32) ----
// MODE 0: acc+bias | 1: acc | 2: alpha[r]*acc+beta[r]*bias | 3: relu(acc+bias) | 4: out+=acc+bias
template <bool LN, int MODE>
__global__ void gemv_k(const float* __restrict__ X, const float* __restrict__ W,
                       const float* __restrict__ bias, const float* __restrict__ gamma,
                       const float* __restrict__ beta_ln, const float* __restrict__ alpha,
                       const float* __restrict__ beta, float* __restrict__ out) {
  __shared__ float XsT[768 * 12];  // [k][r] stride 12
  int t = threadIdx.x;
  int c0 = blockIdx.x * 64, r0 = blockIdx.y * 8;
#pragma unroll
  for (int j = 0; j < 3; ++j) {
    int fidx = j * 512 + t;  // 0..1535
    int r = fidx / 192, c4 = fidx % 192;
    float4 v = *(const float4*)(X + (size_t)(r0 + r) * 768 + c4 * 4);
    int kb = c4 * 4;
    XsT[(kb + 0) * 12 + r] = v.x;
    XsT[(kb + 1) * 12 + r] = v.y;
    XsT[(kb + 2) * 12 + r] = v.z;
    XsT[(kb + 3) * 12 + r] = v.w;
  }
  __syncthreads();
  if (LN) {
    int w = t >> 6, l = t & 63;  // 8 waves, one row each
    float s = 0.f, ss = 0.f;
#pragma unroll
    for (int m = 0; m < 12; ++m) {
      float x = XsT[(l + 64 * m) * 12 + w];
      s += x; ss += x * x;
    }
#pragma unroll
    for (int o = 32; o; o >>= 1) { s += __shfl_xor(s, o); ss += __shfl_xor(ss, o); }
    float mu = s * (1.f / 768.f), rs = rsqrtf(ss * (1.f / 768.f) - mu * mu + LNEPS);
#pragma unroll
    for (int m = 0; m < 12; ++m) {
      int d = l + 64 * m;
      XsT[d * 12 + w] = (XsT[d * 12 + w] - mu) * rs * gamma[d] + beta_ln[d];
    }
    __syncthreads();
  }
  int cx = t & 63, kg = t >> 6;
  int c = c0 + cx;
  float acc[8] = {};
  const float* wp = W + c;
  int k0 = kg * 96;
#pragma unroll 8
  for (int k = k0; k < k0 + 96; ++k) {
    float wv = wp[(size_t)k * 768];
    float4 xa = *(const float4*)&XsT[k * 12];
    float4 xb = *(const float4*)&XsT[k * 12 + 4];
    acc[0] += xa.x * wv; acc[1] += xa.y * wv; acc[2] += xa.z * wv; acc[3] += xa.w * wv;
    acc[4] += xb.x * wv; acc[5] += xb.y * wv; acc[6] += xb.z * wv; acc[7] += xb.w * wv;
  }
  __syncthreads();  // done reading XsT; reuse as reduce buffer
  float* red = XsT;
  if (kg > 0) {
#pragma unroll
    for (int r = 0; r < 8; ++r) red[((kg - 1) * 8 + r) * 64 + cx] = acc[r];
  }
  __syncthreads();
  if (kg == 0) {
#pragma unroll
    for (int g = 1; g < 8; ++g)
#pragma unroll
      for (int r = 0; r < 8; ++r) acc[r] += red[((g - 1) * 8 + r) * 64 + cx];
    float bsc = (MODE == 1) ? 0.f : bias[c];
#pragma unroll
    for (int r = 0; r < 8; ++r) {
      int rr = r0 + r;
      size_t oidx = (size_t)rr * 768 + c;
      float v;
      if (MODE == 0) v = acc[r] + bsc;
      else if (MODE == 1) v = acc[r];
      else if (MODE == 2) v = acc[r] * alpha[rr] + bsc * beta[rr];
      else if (MODE == 3) v = fmaxf(acc[r] + bsc, 0.f);
      else v = out[oidx] + acc[r] + bsc;
      out[oidx] = v;
    }
  }
}

// ---------------- per-slot scalars: Sq = qk.g_in ; c0 = qk.b_in + q.bk ----------------
__global__ void qprep_k(const float* __restrict__ q, const float* __restrict__ qk,
                        const float* __restrict__ g_in, const float* __restrict__ b_in,
                        const float* __restrict__ bk, float* __restrict__ Sqbuf,
                        float* __restrict__ c0buf) {
  int row = blockIdx.x * 4 + (threadIdx.x >> 6), l = threadIdx.x & 63;
  float aS = 0.f, aC = 0.f;
#pragma unroll
  for (int j = 0; j < 12; ++j) {
    int d = l + 64 * j;
    float qkv = qk[(size_t)row * 768 + d];
    aS += qkv * g_in[d];
    aC += qkv * b_in[d] + q[(size_t)row * 768 + d] * bk[d];
  }
#pragma unroll
  for (int o = 32; o; o >>= 1) { aS += __shfl_xor(aS, o); aC += __shfl_xor(aC, o); }
  if (l == 0) { Sqbuf[row] = aS; c0buf[row] = aC; }
}

// ---------------- FUSED dots+softmax+pool, 4 subtiles x 16 rows in LDS ----------------
// grid (16 chunk, 32 b), 512 thr. LDS ~53.6 KB -> 3 blocks/CU. xt stride 384 (wave spans
// 2 adjacent rows -> 2-way banks = free). FIRST computes+stores (mu,r); iters 1-2 load.
template <bool FIRST>
__global__ void __launch_bounds__(512, 2)
dotspool_k(const float* __restrict__ inf, uint32* __restrict__ xh,
           const float* __restrict__ qk, const float* __restrict__ g_in,
           const float* __restrict__ Sqbuf, const float* __restrict__ c0buf,
           f32x2* __restrict__ murbuf, float* __restrict__ attnbuf,
           uint32* __restrict__ partials, float* __restrict__ A0p,
           float* __restrict__ A1p) {
  __shared__ float qkgs[8][768];
  __shared__ uint32 xt[16 * 384];
  __shared__ float oa[64][8], ow[64][8], orm[64];
  __shared__ float c0s[8], Sqs[8];
  int chunk = blockIdx.x, b = blockIdx.y, t = threadIdx.x, l = t & 63;
  for (int i = t; i < 6144; i += 512)
    ((float*)qkgs)[i] = qk[(size_t)b * 6144 + i] * g_in[i % 768];
  if (t < 8) { c0s[t] = c0buf[b * 8 + t]; Sqs[t] = Sqbuf[b * 8 + t]; }
  int g32 = t & 31, gid = t >> 5;  // 16 groups of 32 lanes; group -> row
  f32x2 pacc[8] = {};
#pragma unroll
  for (int sub = 0; sub < 4; ++sub) {
    if (FIRST) {
      const float4* xpf =
          (const float4*)(inf + ((size_t)b * 1024 + chunk * 64 + sub * 16) * 768);
      uint2* xg = (uint2*)(xh + ((size_t)b * 1024 + chunk * 64 + sub * 16) * 384);
#pragma unroll
      for (int j = 0; j < 6; ++j) {
        int idx = j * 512 + t;  // 3072 float4s
        int row = idx / 192, c4 = idx % 192;
        float4 v = xpf[(size_t)row * 192 + c4];
        uint2 o;
        o.x = bfb(v.x) | (bfb(v.y) << 16);
        o.y = bfb(v.z) | (bfb(v.w) << 16);
        *(uint2*)&xt[row * 384 + c4 * 2] = o;
        xg[(size_t)row * 192 + c4] = o;
      }
    } else {
      const uint4* xps4 = (const uint4*)(xh + ((size_t)b * 1024 + chunk * 64 + sub * 16) * 384);
#pragma unroll
      for (int j = 0; j < 3; ++j) {
        int idx = j * 512 + t;  // 1536 uint4s
        int row = idx / 96, c4 = idx % 96;
        *(uint4*)&xt[row * 384 + c4 * 4] = xps4[idx];
      }
    }
    __syncthreads();
    // dots+softmax: group gid owns row sub*16+gid
    {
      int lr = sub * 16 + gid;
      size_t grow = (size_t)b * 1024 + chunk * 64 + lr;
      const uint32* xr = &xt[gid * 384];
      float mu, r;
      f32x2 ds2[8] = {};
      if (FIRST) {
        f32x2 sv = {0.f, 0.f}, ssv = {0.f, 0.f};
#pragma unroll 4
        for (int j = 0; j < 12; ++j) {
          f32x2 ab = unpk(xr[j * 32 + g32]);
          sv += ab;
          ssv += ab * ab;
          int d0 = 2 * (j * 32 + g32);
#pragma unroll
          for (int s2 = 0; s2 < 8; ++s2) {
            f32x2 qg = *(const f32x2*)&qkgs[s2][d0];
            ds2[s2] += qg * ab;
          }
        }
        float s = sv.x + sv.y, ss = ssv.x + ssv.y;
        float ds[8];
#pragma unroll
        for (int s2 = 0; s2 < 8; ++s2) ds[s2] = ds2[s2].x + ds2[s2].y;
#pragma unroll
        for (int o = 1; o < 32; o <<= 1) {
          s += __shfl_xor(s, o);
          ss += __shfl_xor(ss, o);
#pragma unroll
          for (int s2 = 0; s2 < 8; ++s2) ds[s2] += __shfl_xor(ds[s2], o);
        }
        mu = s * (1.f / 768.f);
        r = rsqrtf(ss * (1.f / 768.f) - mu * mu + LNEPS);
        if (g32 == 8) { f32x2 m2; m2.x = mu; m2.y = r; murbuf[grow] = m2; }
        float rmu = r * mu;
        float sc[8];
#pragma unroll
        for (int s2 = 0; s2 < 8; ++s2)
          sc[s2] = (r * ds[s2] - rmu * Sqs[s2] + c0s[s2]) * SCALE_Q;
        float mx = sc[0];
#pragma unroll
        for (int s2 = 1; s2 < 8; ++s2) mx = fmaxf(mx, sc[s2]);
        float e[8], se = 0.f;
#pragma unroll
        for (int s2 = 0; s2 < 8; ++s2) { e[s2] = __expf(sc[s2] - mx); se += e[s2]; }
        float inv_se = 1.f / se;
        float av = e[0];
#pragma unroll
        for (int s2 = 1; s2 < 8; ++s2) av = (g32 == s2) ? e[s2] : av;
        av *= inv_se;
        if (g32 < 8) { oa[lr][g32] = av; ow[lr][g32] = av * r; }
        if (g32 == 8) orm[lr] = rmu;
      } else {
#pragma unroll 4
        for (int j = 0; j < 12; ++j) {
          f32x2 ab = unpk(xr[j * 32 + g32]);
          int d0 = 2 * (j * 32 + g32);
#pragma unroll
          for (int s2 = 0; s2 < 8; ++s2) {
            f32x2 qg = *(const f32x2*)&qkgs[s2][d0];
            ds2[s2] += qg * ab;
          }
        }
        float ds[8];
#pragma unroll
        for (int s2 = 0; s2 < 8; ++s2) ds[s2] = ds2[s2].x + ds2[s2].y;
#pragma unroll
        for (int o = 1; o < 32; o <<= 1) {
#pragma unroll
          for (int s2 = 0; s2 < 8; ++s2) ds[s2] += __shfl_xor(ds[s2], o);
        }
        f32x2 mur = murbuf[grow];
        mu = mur.x; r = mur.y;
        float rmu = r * mu;
        float sc[8];
#pragma unroll
        for (int s2 = 0; s2 < 8; ++s2)
          sc[s2] = (r * ds[s2] - rmu * Sqs[s2] + c0s[s2]) * SCALE_Q;
        float mx = sc[0];
#pragma unroll
        for (int s2 = 1; s2 < 8; ++s2) mx = fmaxf(mx, sc[s2]);
        float e[8], se = 0.f;
#pragma unroll
        for (int s2 = 0; s2 < 8; ++s2) { e[s2] = __expf(sc[s2] - mx); se += e[s2]; }
        float inv_se = 1.f / se;
        float av = e[0];
#pragma unroll
        for (int s2 = 1; s2 < 8; ++s2) av = (g32 == s2) ? e[s2] : av;
        av *= inv_se;
        if (g32 < 8) { oa[lr][g32] = av; ow[lr][g32] = av * r; }
        if (g32 == 8) orm[lr] = rmu;
      }
    }
    __syncthreads();
    // pool this subtile from LDS (threads 0..383 own one packed col)
    if (t < 384) {
#pragma unroll 2
      for (int nn = 0; nn < 16; ++nn) {
        f32x2 xv = unpk(xt[nn * 384 + t]);
        const float* owr = &ow[sub * 16 + nn][0];
#pragma unroll
        for (int k = 0; k < 4; ++k) {
          f32x2 owv = *(const f32x2*)&owr[2 * k];
          pacc[2 * k] += owv.x * xv;
          pacc[2 * k + 1] += owv.y * xv;
        }
      }
    } else if (sub == 3 && t < 392) {
      int sl = t - 384;
      float A0 = 0.f, A1 = 0.f;
      for (int rr2 = 0; rr2 < 64; ++rr2) {
        float a = oa[rr2][sl];
        A0 += a;
        A1 += a * orm[rr2];
      }
      A0p[chunk * 256 + b * 8 + sl] = A0;
      A1p[chunk * 256 + b * 8 + sl] = A1;
    }
    __syncthreads();
  }
  if (t < 384) {
#pragma unroll
    for (int s2 = 0; s2 < 8; ++s2) {
      size_t base = ((size_t)(chunk * 256 + b * 8 + s2)) * 384;
      partials[base + t] = bfb(pacc[s2].x) | (bfb(pacc[s2].y) << 16);
    }
  }
  size_t base8 = ((size_t)b * 1024 + chunk * 64) * 8;
  attnbuf[base8 + t] = oa[t >> 3][t & 7];
}

// ---------------- reduce packed partials + A0/A1 + LN-fixup -> pooled ; inv, rho --------
// grid 256 (row = b*8+s), 384 thr (one d-pair each)
__global__ void reduce_fix_k(const uint32* __restrict__ partials, const float* __restrict__ A0p,
                             const float* __restrict__ A1p, const float* __restrict__ g_in,
                             const float* __restrict__ b_in, float* __restrict__ pooled,
                             float* __restrict__ invbuf, float* __restrict__ rhobuf) {
  int row = blockIdx.x, t = threadIdx.x;  // row = b*8+s ; t = d-pair index
  float A0 = 0.f, A1 = 0.f;
#pragma unroll
  for (int ch = 0; ch < 16; ++ch) {
    A0 += A0p[ch * 256 + row];
    A1 += A1p[ch * 256 + row];
  }
  f32x2 a = {0.f, 0.f};
#pragma unroll
  for (int ch = 0; ch < 16; ++ch)
    a += unpk(partials[((size_t)(ch * 256 + row)) * 384 + t]);
  int d = 2 * t;
  f32x2 g = *(const f32x2*)&g_in[d];
  f32x2 bi = *(const f32x2*)&b_in[d];
  f32x2 res;
  res.x = g.x * (a.x - A1) + bi.x * A0;
  res.y = g.y * (a.y - A1) + bi.y * A0;
  *(f32x2*)&pooled[(size_t)row * 768 + d] = res;
  if (t == 0) {
    float iv = 1.f / (A0 + AEPS);
    invbuf[row] = iv;
    rhobuf[row] = A0 * iv;
  }
}

// ---------------- merged output writer (fp32) ----------------
__global__ void outs_k(const float* __restrict__ slots, const float* __restrict__ attnbuf,
                       const float* __restrict__ invbuf, float* __restrict__ out) {
  int i = blockIdx.x * 256 + threadIdx.x;  // 458752
  if (i < 196608) {
    out[i] = slots[i];
  } else {
    int j = i - 196608;  // [b][n][s]
    out[i] = attnbuf[j] * invbuf[((j >> 13) << 3) + (j & 7)];
  }
}

extern "C" void kernel_launch(void* const* d_in, const int* in_sizes, int n_in,
                              void* d_out, int out_size, void* d_ws, size_t ws_size,
                              hipStream_t stream) {
  (void)in_sizes; (void)n_in; (void)out_size; (void)ws_size;
  const float* slots0 = (const float*)d_in[0];
  const float* inputs = (const float*)d_in[1];
  const float* Wq = (const float*)d_in[2];
  const float* bq = (const float*)d_in[3];
  const float* Wk = (const float*)d_in[4];
  const float* bk = (const float*)d_in[5];
  const float* Wv = (const float*)d_in[6];
  const float* bv = (const float*)d_in[7];
  const float* g_in = (const float*)d_in[8];
  const float* b_in = (const float*)d_in[9];
  const float* g_s = (const float*)d_in[10];
  const float* b_s = (const float*)d_in[11];
  const float* g_ff = (const float*)d_in[12];
  const float* b_ff = (const float*)d_in[13];
  const float* W1 = (const float*)d_in[14];
  const float* b1 = (const float*)d_in[15];
  const float* W2 = (const float*)d_in[16];
  const float* b2 = (const float*)d_in[17];

  char* p = (char*)d_ws;
  uint32* xh = (uint32*)p;     p += (size_t)32768 * 384 * 4;  // packed bf16 inputs
  f32x2* murbuf = (f32x2*)p;   p += (size_t)32768 * 8;        // per-row (mu, rstd)
  float* WkT = (float*)p;      p += (size_t)768 * 768 * 4;
  float* slotsf = (float*)p;   p += 256 * 768 * 4;
  float* qbuf = (float*)p;     p += 256 * 768 * 4;
  float* qkbuf = (float*)p;    p += 256 * 768 * 4;
  float* Sqbuf = (float*)p;    p += 256 * 4;
  float* c0buf = (float*)p;    p += 256 * 4;
  float* attnbuf = (float*)p;  p += (size_t)32768 * 8 * 4;
  uint32* partials = (uint32*)p; p += (size_t)16 * 256 * 384 * 4;  // packed bf16 pairs
  float* A0p = (float*)p;      p += 16 * 256 * 4;
  float* A1p = (float*)p;      p += 16 * 256 * 4;
  float* pooled = (float*)p;   p += 256 * 768 * 4;
  float* invbuf = (float*)p;   p += 256 * 4;
  float* rhobuf = (float*)p;   p += 256 * 4;
  float* updbuf = (float*)p;   p += 256 * 768 * 4;
  float* t1buf = (float*)p;    p += 256 * 768 * 4;

  dim3 ggrid(12, 32);
  setup_k<<<1344, 256, 0, stream>>>(Wk, WkT, slots0, slotsf);
  for (int it = 0; it < 3; ++it) {
    gemv_k<true, 0><<<ggrid, 512, 0, stream>>>(slotsf, Wq, bq, g_s, b_s, nullptr, nullptr,
                                               qbuf);
    gemv_k<false, 1><<<ggrid, 512, 0, stream>>>(qbuf, WkT, nullptr, nullptr, nullptr, nullptr,
                                                nullptr, qkbuf);
    qprep_k<<<64, 256, 0, stream>>>(qbuf, qkbuf, g_in, b_in, bk, Sqbuf, c0buf);
    if (it == 0)
      dotspool_k<true><<<dim3(16, 32), 512, 0, stream>>>(inputs, xh, qkbuf, g_in, Sqbuf,
                                                         c0buf, murbuf, attnbuf, partials,
                                                         A0p, A1p);
    else
      dotspool_k<false><<<dim3(16, 32), 512, 0, stream>>>(inputs, xh, qkbuf, g_in, Sqbuf,
                                                          c0buf, murbuf, attnbuf, partials,
                                                          A0p, A1p);
    reduce_fix_k<<<256, 384, 0, stream>>>(partials, A0p, A1p, g_in, b_in, pooled,
                                          invbuf, rhobuf);
    gemv_k<false, 2><<<ggrid, 512, 0, stream>>>(pooled, Wv, bv, nullptr, nullptr, invbuf,
                                                rhobuf, updbuf);
    gemv_k<true, 3><<<ggrid, 512, 0, stream>>>(updbuf, W1, b1, g_ff, b_ff, nullptr, nullptr,
                                               t1buf);
    gemv_k<false, 4><<<ggrid, 512, 0, stream>>>(t1buf, W2, b2, nullptr, nullptr, nullptr,
                                                nullptr, slotsf);
  }
  outs_k<<<1792, 256, 0, stream>>>(slotsf, attnbuf, invbuf, (float*)d_out);
}

// Round 20
// 330.097 us; speedup vs baseline: 1.0617x; 1.0040x over previous
//
#include <hip/hip_runtime.h>

#define LNEPS 1e-5f
#define AEPS 1e-8f
#define SCALE_Q 0.036084391824351615f  // 768^-0.5

typedef unsigned int uint32;
typedef float f32x2 __attribute__((ext_vector_type(2)));

__device__ inline uint32 bfb(float f) {
  __bf16 h = (__bf16)f;
  unsigned short u;
  __builtin_memcpy(&u, &h, 2);
  return (uint32)u;
}
__device__ inline f32x2 unpk(uint32 u) {
  f32x2 v;
  v.x = __uint_as_float(u << 16);
  v.y = __uint_as_float(u & 0xffff0000u);
  return v;
}

// ---------------- one-time setup: packT Wk | init slots ----------------
__global__ void setup_k(const float* __restrict__ Wk, float* __restrict__ WkT,
                        const float* __restrict__ s0, float* __restrict__ slots) {
  __shared__ float tile[32][33];
  int bb = blockIdx.x, t = threadIdx.x;
  if (bb < 576) {
    int c0 = (bb % 24) * 32, i0 = (bb / 24) * 32;
    int tx = t & 31, ty = t >> 5;
#pragma unroll
    for (int k = 0; k < 4; ++k)
      tile[ty + 8 * k][tx] = Wk[(size_t)(i0 + ty + 8 * k) * 768 + c0 + tx];
    __syncthreads();
#pragma unroll
    for (int k = 0; k < 4; ++k)
      WkT[(size_t)(c0 + ty + 8 * k) * 768 + i0 + tx] = tile[tx][ty + 8 * k];
  } else {
    int idx = (bb - 576) * 256 + t;  // 196608
    slots[idx] = s0[idx % 6144];
  }
}

// ---------------- batched GEMV v3: 64 cols/block, 8-way k-split, 512 thr, grid (12,32) ----
// MODE 0: acc+bias | 1: acc | 2: alpha[r]*acc+beta[r]*bias | 3: relu(acc+bias) | 4: out+=acc+bias
template <bool LN, int MODE>
__global__ void gemv_k(const float* __restrict__ X, const float* __restrict__ W,
                       const float* __restrict__ bias, const float* __restrict__ gamma,
                       const float* __restrict__ beta_ln, const float* __restrict__ alpha,
                       const float* __restrict__ beta, float* __restrict__ out) {
  __shared__ float XsT[768 * 12];  // [k][r] stride 12
  int t = threadIdx.x;
  int c0 = blockIdx.x * 64, r0 = blockIdx.y * 8;
#pragma unroll
  for (int j = 0; j < 3; ++j) {
    int fidx = j * 512 + t;  // 0..1535
    int r = fidx / 192, c4 = fidx % 192;
    float4 v = *(const float4*)(X + (size_t)(r0 + r) * 768 + c4 * 4);
    int kb = c4 * 4;
    XsT[(kb + 0) * 12 + r] = v.x;
    XsT[(kb + 1) * 12 + r] = v.y;
    XsT[(kb + 2) * 12 + r] = v.z;
    XsT[(kb + 3) * 12 + r] = v.w;
  }
  __syncthreads();
  if (LN) {
    int w = t >> 6, l = t & 63;  // 8 waves, one row each
    float s = 0.f, ss = 0.f;
#pragma unroll
    for (int m = 0; m < 12; ++m) {
      float x = XsT[(l + 64 * m) * 12 + w];
      s += x; ss += x * x;
    }
#pragma unroll
    for (int o = 32; o; o >>= 1) { s += __shfl_xor(s, o); ss += __shfl_xor(ss, o); }
    float mu = s * (1.f / 768.f), rs = rsqrtf(ss * (1.f / 768.f) - mu * mu + LNEPS);
#pragma unroll
    for (int m = 0; m < 12; ++m) {
      int d = l + 64 * m;
      XsT[d * 12 + w] = (XsT[d * 12 + w] - mu) * rs * gamma[d] + beta_ln[d];
    }
    __syncthreads();
  }
  int cx = t & 63, kg = t >> 6;
  int c = c0 + cx;
  float acc[8] = {};
  const float* wp = W + c;
  int k0 = kg * 96;
#pragma unroll 8
  for (int k = k0; k < k0 + 96; ++k) {
    float wv = wp[(size_t)k * 768];
    float4 xa = *(const float4*)&XsT[k * 12];
    float4 xb = *(const float4*)&XsT[k * 12 + 4];
    acc[0] += xa.x * wv; acc[1] += xa.y * wv; acc[2] += xa.z * wv; acc[3] += xa.w * wv;
    acc[4] += xb.x * wv; acc[5] += xb.y * wv; acc[6] += xb.z * wv; acc[7] += xb.w * wv;
  }
  __syncthreads();  // done reading XsT; reuse as reduce buffer
  float* red = XsT;
  if (kg > 0) {
#pragma unroll
    for (int r = 0; r < 8; ++r) red[((kg - 1) * 8 + r) * 64 + cx] = acc[r];
  }
  __syncthreads();
  if (kg == 0) {
#pragma unroll
    for (int g = 1; g < 8; ++g)
#pragma unroll
      for (int r = 0; r < 8; ++r) acc[r] += red[((g - 1) * 8 + r) * 64 + cx];
    float bsc = (MODE == 1) ? 0.f : bias[c];
#pragma unroll
    for (int r = 0; r < 8; ++r) {
      int rr = r0 + r;
      size_t oidx = (size_t)rr * 768 + c;
      float v;
      if (MODE == 0) v = acc[r] + bsc;
      else if (MODE == 1) v = acc[r];
      else if (MODE == 2) v = acc[r] * alpha[rr] + bsc * beta[rr];
      else if (MODE == 3) v = fmaxf(acc[r] + bsc, 0.f);
      else v = out[oidx] + acc[r] + bsc;
      out[oidx] = v;
    }
  }
}

// ---------------- per-slot scalars: Sq = qk.g_in ; c0 = qk.b_in + q.bk ----------------
__global__ void qprep_k(const float* __restrict__ q, const float* __restrict__ qk,
                        const float* __restrict__ g_in, const float* __restrict__ b_in,
                        const float* __restrict__ bk, float* __restrict__ Sqbuf,
                        float* __restrict__ c0buf) {
  int row = blockIdx.x * 4 + (threadIdx.x >> 6), l = threadIdx.x & 63;
  float aS = 0.f, aC = 0.f;
#pragma unroll
  for (int j = 0; j < 12; ++j) {
    int d = l + 64 * j;
    float qkv = qk[(size_t)row * 768 + d];
    aS += qkv * g_in[d];
    aC += qkv * b_in[d] + q[(size_t)row * 768 + d] * bk[d];
  }
#pragma unroll
  for (int o = 32; o; o >>= 1) { aS += __shfl_xor(aS, o); aC += __shfl_xor(aC, o); }
  if (l == 0) { Sqbuf[row] = aS; c0buf[row] = aC; }
}

// ---------------- FUSED dots+softmax+pool, 4 subtiles x 16 rows in LDS ----------------
// grid (16 chunk, 32 b), 512 thr. Launch bounds relaxed to (512,1): allow VGPR up to 256
// so the ~50-reg live set never spills (r16-r19 showed a constant ~45 MB phantom WRITE).
template <bool FIRST>
__global__ void __launch_bounds__(512, 1)
dotspool_k(const float* __restrict__ inf, uint32* __restrict__ xh,
           const float* __restrict__ qk, const float* __restrict__ g_in,
           const float* __restrict__ Sqbuf, const float* __restrict__ c0buf,
           f32x2* __restrict__ murbuf, float* __restrict__ attnbuf,
           uint32* __restrict__ partials, float* __restrict__ A0p,
           float* __restrict__ A1p) {
  __shared__ float qkgs[8][768];
  __shared__ uint32 xt[16 * 384];
  __shared__ float oa[64][8], ow[64][8], orm[64];
  __shared__ float c0s[8], Sqs[8];
  int chunk = blockIdx.x, b = blockIdx.y, t = threadIdx.x;
  for (int i = t; i < 6144; i += 512)
    ((float*)qkgs)[i] = qk[(size_t)b * 6144 + i] * g_in[i % 768];
  if (t < 8) { c0s[t] = c0buf[b * 8 + t]; Sqs[t] = Sqbuf[b * 8 + t]; }
  int g32 = t & 31, gid = t >> 5;  // 16 groups of 32 lanes; group -> row
  f32x2 pacc[8] = {};
#pragma unroll
  for (int sub = 0; sub < 4; ++sub) {
    if (FIRST) {
      const float4* xpf =
          (const float4*)(inf + ((size_t)b * 1024 + chunk * 64 + sub * 16) * 768);
      uint2* xg = (uint2*)(xh + ((size_t)b * 1024 + chunk * 64 + sub * 16) * 384);
#pragma unroll
      for (int j = 0; j < 6; ++j) {
        int idx = j * 512 + t;  // 3072 float4s
        int row = idx / 192, c4 = idx % 192;
        float4 v = xpf[(size_t)row * 192 + c4];
        uint2 o;
        o.x = bfb(v.x) | (bfb(v.y) << 16);
        o.y = bfb(v.z) | (bfb(v.w) << 16);
        *(uint2*)&xt[row * 384 + c4 * 2] = o;
        xg[(size_t)row * 192 + c4] = o;
      }
    } else {
      const uint4* xps4 = (const uint4*)(xh + ((size_t)b * 1024 + chunk * 64 + sub * 16) * 384);
#pragma unroll
      for (int j = 0; j < 3; ++j) {
        int idx = j * 512 + t;  // 1536 uint4s
        int row = idx / 96, c4 = idx % 96;
        *(uint4*)&xt[row * 384 + c4 * 4] = xps4[idx];
      }
    }
    __syncthreads();
    // dots+softmax: group gid owns row sub*16+gid
    {
      int lr = sub * 16 + gid;
      size_t grow = (size_t)b * 1024 + chunk * 64 + lr;
      const uint32* xr = &xt[gid * 384];
      float mu, r;
      f32x2 ds2[8] = {};
      if (FIRST) {
        f32x2 sv = {0.f, 0.f}, ssv = {0.f, 0.f};
#pragma unroll 4
        for (int j = 0; j < 12; ++j) {
          f32x2 ab = unpk(xr[j * 32 + g32]);
          sv += ab;
          ssv += ab * ab;
          int d0 = 2 * (j * 32 + g32);
#pragma unroll
          for (int s2 = 0; s2 < 8; ++s2) {
            f32x2 qg = *(const f32x2*)&qkgs[s2][d0];
            ds2[s2] += qg * ab;
          }
        }
        float s = sv.x + sv.y, ss = ssv.x + ssv.y;
        float ds[8];
#pragma unroll
        for (int s2 = 0; s2 < 8; ++s2) ds[s2] = ds2[s2].x + ds2[s2].y;
#pragma unroll
        for (int o = 1; o < 32; o <<= 1) {
          s += __shfl_xor(s, o);
          ss += __shfl_xor(ss, o);
#pragma unroll
          for (int s2 = 0; s2 < 8; ++s2) ds[s2] += __shfl_xor(ds[s2], o);
        }
        mu = s * (1.f / 768.f);
        r = rsqrtf(ss * (1.f / 768.f) - mu * mu + LNEPS);
        if (g32 == 8) { f32x2 m2; m2.x = mu; m2.y = r; murbuf[grow] = m2; }
        float rmu = r * mu;
        float sc[8];
#pragma unroll
        for (int s2 = 0; s2 < 8; ++s2)
          sc[s2] = (r * ds[s2] - rmu * Sqs[s2] + c0s[s2]) * SCALE_Q;
        float mx = sc[0];
#pragma unroll
        for (int s2 = 1; s2 < 8; ++s2) mx = fmaxf(mx, sc[s2]);
        float e[8], se = 0.f;
#pragma unroll
        for (int s2 = 0; s2 < 8; ++s2) { e[s2] = __expf(sc[s2] - mx); se += e[s2]; }
        float inv_se = 1.f / se;
        float av = e[0];
#pragma unroll
        for (int s2 = 1; s2 < 8; ++s2) av = (g32 == s2) ? e[s2] : av;
        av *= inv_se;
        if (g32 < 8) { oa[lr][g32] = av; ow[lr][g32] = av * r; }
        if (g32 == 8) orm[lr] = rmu;
      } else {
#pragma unroll 4
        for (int j = 0; j < 12; ++j) {
          f32x2 ab = unpk(xr[j * 32 + g32]);
          int d0 = 2 * (j * 32 + g32);
#pragma unroll
          for (int s2 = 0; s2 < 8; ++s2) {
            f32x2 qg = *(const f32x2*)&qkgs[s2][d0];
            ds2[s2] += qg * ab;
          }
        }
        float ds[8];
#pragma unroll
        for (int s2 = 0; s2 < 8; ++s2) ds[s2] = ds2[s2].x + ds2[s2].y;
#pragma unroll
        for (int o = 1; o < 32; o <<= 1) {
#pragma unroll
          for (int s2 = 0; s2 < 8; ++s2) ds[s2] += __shfl_xor(ds[s2], o);
        }
        f32x2 mur = murbuf[grow];
        mu = mur.x; r = mur.y;
        float rmu = r * mu;
        float sc[8];
#pragma unroll
        for (int s2 = 0; s2 < 8; ++s2)
          sc[s2] = (r * ds[s2] - rmu * Sqs[s2] + c0s[s2]) * SCALE_Q;
        float mx = sc[0];
#pragma unroll
        for (int s2 = 1; s2 < 8; ++s2) mx = fmaxf(mx, sc[s2]);
        float e[8], se = 0.f;
#pragma unroll
        for (int s2 = 0; s2 < 8; ++s2) { e[s2] = __expf(sc[s2] - mx); se += e[s2]; }
        float inv_se = 1.f / se;
        float av = e[0];
#pragma unroll
        for (int s2 = 1; s2 < 8; ++s2) av = (g32 == s2) ? e[s2] : av;
        av *= inv_se;
        if (g32 < 8) { oa[lr][g32] = av; ow[lr][g32] = av * r; }
        if (g32 == 8) orm[lr] = rmu;
      }
    }
    __syncthreads();
    // pool this subtile from LDS (threads 0..383 own one packed col)
    if (t < 384) {
#pragma unroll 2
      for (int nn = 0; nn < 16; ++nn) {
        f32x2 xv = unpk(xt[nn * 384 + t]);
        const float* owr = &ow[sub * 16 + nn][0];
#pragma unroll
        for (int k = 0; k < 4; ++k) {
          f32x2 owv = *(const f32x2*)&owr[2 * k];
          pacc[2 * k] += owv.x * xv;
          pacc[2 * k + 1] += owv.y * xv;
        }
      }
    } else if (sub == 3 && t < 392) {
      int sl = t - 384;
      float A0 = 0.f, A1 = 0.f;
      for (int rr2 = 0; rr2 < 64; ++rr2) {
        float a = oa[rr2][sl];
        A0 += a;
        A1 += a * orm[rr2];
      }
      A0p[chunk * 256 + b * 8 + sl] = A0;
      A1p[chunk * 256 + b * 8 + sl] = A1;
    }
    __syncthreads();
  }
  if (t < 384) {
#pragma unroll
    for (int s2 = 0; s2 < 8; ++s2) {
      size_t base = ((size_t)(chunk * 256 + b * 8 + s2)) * 384;
      partials[base + t] = bfb(pacc[s2].x) | (bfb(pacc[s2].y) << 16);
    }
  }
  size_t base8 = ((size_t)b * 1024 + chunk * 64) * 8;
  attnbuf[base8 + t] = oa[t >> 3][t & 7];
}

// ---------------- reduce packed partials + A0/A1 + LN-fixup -> pooled ; inv, rho --------
// grid 256 (row = b*8+s), 384 thr (one d-pair each)
__global__ void reduce_fix_k(const uint32* __restrict__ partials, const float* __restrict__ A0p,
                             const float* __restrict__ A1p, const float* __restrict__ g_in,
                             const float* __restrict__ b_in, float* __restrict__ pooled,
                             float* __restrict__ invbuf, float* __restrict__ rhobuf) {
  int row = blockIdx.x, t = threadIdx.x;  // row = b*8+s ; t = d-pair index
  float A0 = 0.f, A1 = 0.f;
#pragma unroll
  for (int ch = 0; ch < 16; ++ch) {
    A0 += A0p[ch * 256 + row];
    A1 += A1p[ch * 256 + row];
  }
  f32x2 a = {0.f, 0.f};
#pragma unroll
  for (int ch = 0; ch < 16; ++ch)
    a += unpk(partials[((size_t)(ch * 256 + row)) * 384 + t]);
  int d = 2 * t;
  f32x2 g = *(const f32x2*)&g_in[d];
  f32x2 bi = *(const f32x2*)&b_in[d];
  f32x2 res;
  res.x = g.x * (a.x - A1) + bi.x * A0;
  res.y = g.y * (a.y - A1) + bi.y * A0;
  *(f32x2*)&pooled[(size_t)row * 768 + d] = res;
  if (t == 0) {
    float iv = 1.f / (A0 + AEPS);
    invbuf[row] = iv;
    rhobuf[row] = A0 * iv;
  }
}

// ---------------- merged output writer (fp32) ----------------
__global__ void outs_k(const float* __restrict__ slots, const float* __restrict__ attnbuf,
                       const float* __restrict__ invbuf, float* __restrict__ out) {
  int i = blockIdx.x * 256 + threadIdx.x;  // 458752
  if (i < 196608) {
    out[i] = slots[i];
  } else {
    int j = i - 196608;  // [b][n][s]
    out[i] = attnbuf[j] * invbuf[((j >> 13) << 3) + (j & 7)];
  }
}

extern "C" void kernel_launch(void* const* d_in, const int* in_sizes, int n_in,
                              void* d_out, int out_size, void* d_ws, size_t ws_size,
                              hipStream_t stream) {
  (void)in_sizes; (void)n_in; (void)out_size; (void)ws_size;
  const float* slots0 = (const float*)d_in[0];
  const float* inputs = (const float*)d_in[1];
  const float* Wq = (const float*)d_in[2];
  const float* bq = (const float*)d_in[3];
  const float* Wk = (const float*)d_in[4];
  const float* bk = (const float*)d_in[5];
  const float* Wv = (const float*)d_in[6];
  const float* bv = (const float*)d_in[7];
  const float* g_in = (const float*)d_in[8];
  const float* b_in = (const float*)d_in[9];
  const float* g_s = (const float*)d_in[10];
  const float* b_s = (const float*)d_in[11];
  const float* g_ff = (const float*)d_in[12];
  const float* b_ff = (const float*)d_in[13];
  const float* W1 = (const float*)d_in[14];
  const float* b1 = (const float*)d_in[15];
  const float* W2 = (const float*)d_in[16];
  const float* b2 = (const float*)d_in[17];

  char* p = (char*)d_ws;
  uint32* xh = (uint32*)p;     p += (size_t)32768 * 384 * 4;  // packed bf16 inputs
  f32x2* murbuf = (f32x2*)p;   p += (size_t)32768 * 8;        // per-row (mu, rstd)
  float* WkT = (float*)p;      p += (size_t)768 * 768 * 4;
  float* slotsf = (float*)p;   p += 256 * 768 * 4;
  float* qbuf = (float*)p;     p += 256 * 768 * 4;
  float* qkbuf = (float*)p;    p += 256 * 768 * 4;
  float* Sqbuf = (float*)p;    p += 256 * 4;
  float* c0buf = (float*)p;    p += 256 * 4;
  float* attnbuf = (float*)p;  p += (size_t)32768 * 8 * 4;
  uint32* partials = (uint32*)p; p += (size_t)16 * 256 * 384 * 4;  // packed bf16 pairs
  float* A0p = (float*)p;      p += 16 * 256 * 4;
  float* A1p = (float*)p;      p += 16 * 256 * 4;
  float* pooled = (float*)p;   p += 256 * 768 * 4;
  float* invbuf = (float*)p;   p += 256 * 4;
  float* rhobuf = (float*)p;   p += 256 * 4;
  float* updbuf = (float*)p;   p += 256 * 768 * 4;
  float* t1buf = (float*)p;    p += 256 * 768 * 4;

  dim3 ggrid(12, 32);
  setup_k<<<1344, 256, 0, stream>>>(Wk, WkT, slots0, slotsf);
  for (int it = 0; it < 3; ++it) {
    gemv_k<true, 0><<<ggrid, 512, 0, stream>>>(slotsf, Wq, bq, g_s, b_s, nullptr, nullptr,
                                               qbuf);
    gemv_k<false, 1><<<ggrid, 512, 0, stream>>>(qbuf, WkT, nullptr, nullptr, nullptr, nullptr,
                                                nullptr, qkbuf);
    qprep_k<<<64, 256, 0, stream>>>(qbuf, qkbuf, g_in, b_in, bk, Sqbuf, c0buf);
    if (it == 0)
      dotspool_k<true><<<dim3(16, 32), 512, 0, stream>>>(inputs, xh, qkbuf, g_in, Sqbuf,
                                                         c0buf, murbuf, attnbuf, partials,
                                                         A0p, A1p);
    else
      dotspool_k<false><<<dim3(16, 32), 512, 0, stream>>>(inputs, xh, qkbuf, g_in, Sqbuf,
                                                          c0buf, murbuf, attnbuf, partials,
                                                          A0p, A1p);
    reduce_fix_k<<<256, 384, 0, stream>>>(partials, A0p, A1p, g_in, b_in, pooled,
                                          invbuf, rhobuf);
    gemv_k<false, 2><<<ggrid, 512, 0, stream>>>(pooled, Wv, bv, nullptr, nullptr, invbuf,
                                                rhobuf, updbuf);
    gemv_k<true, 3><<<ggrid, 512, 0, stream>>>(updbuf, W1, b1, g_ff, b_ff, nullptr, nullptr,
                                               t1buf);
    gemv_k<false, 4><<<ggrid, 512, 0, stream>>>(t1buf, W2, b2, nullptr, nullptr, nullptr,
                                                nullptr, slotsf);
  }
  outs_k<<<1792, 256, 0, stream>>>(slotsf, attnbuf, invbuf, (float*)d_out);
}